// Round 5
// baseline (122.104 us; speedup 1.0000x reference)
//
#include <hip/hip_runtime.h>

// AlignOnlySubLayer: out[b,m,d] = main[b,m,d] - sum_c softmax_m(C·M^T)[c,m] * C[c,d]
// B=8, Lc=Lm=2048, D=128, fp32 in/out.
// Round-5 pipeline (bf16 intermediates, 16B-chunk XOR swizzle, global_load_lds):
//   convert: Cbf/Mbf = bf16(ctx/main) swizzled; Lg = 0
//   stats  : E[b,m,c] = bf16(exp(S-40)) DIRECT register->global (swizzled b64 stores,
//            no LDS round-trip); M double-buffered, ONE barrier/tile; L via atomics
//   prep   : CtL[b,d,c] = bf16(C[b,c,d]/L[b,c]) transposed + swizzled
//   attend : out = main - E · CtL  (dbuf async-staged MFMA GEMM, K=2048, XCD-swizzled)
// Swizzle: chunk pc = lc ^ (row & 7) within 8-chunk groups; frag reads at
// ((ks*4+q) ^ (a15&7)) hit exactly 8 words/bank per ds_read_b128.

#define BATCH 8
#define L_SEQ 2048
#define DD 128
#define SHIFT 40.0f
#define LDA 136   // fallback/prep padded stride

typedef __attribute__((ext_vector_type(8))) short bf16x8;
typedef __attribute__((ext_vector_type(4))) short bf16x4;
typedef __attribute__((ext_vector_type(4))) float f32x4;

__device__ __forceinline__ short f2bf(float f) {
    unsigned u = __builtin_bit_cast(unsigned, f);
    return (short)((u + 0x8000u) >> 16);
}

// Async global->LDS, 16 B per lane. LDS dest = uniform base + lane*16.
__device__ __forceinline__ void gl2lds16(const short* g, short* l) {
    __builtin_amdgcn_global_load_lds(
        (const __attribute__((address_space(1))) unsigned int*)g,
        (__attribute__((address_space(3))) unsigned int*)l, 16, 0, 0);
}

// fp32 global (rows of 128) -> bf16 LDS tile, stride LDA (fallback path only).
template <int NT>
__device__ __forceinline__ void stage_tile(short* __restrict__ dst,
                                           const float* __restrict__ src,
                                           int nelts, int t) {
    for (int base = 0; base < nelts; base += NT * 8) {
        int flat = base + t * 8;
        const float4* p = (const float4*)(src + flat);
        float4 v0 = p[0];
        float4 v1 = p[1];
        bf16x8 s;
        s[0] = f2bf(v0.x); s[1] = f2bf(v0.y); s[2] = f2bf(v0.z); s[3] = f2bf(v0.w);
        s[4] = f2bf(v1.x); s[5] = f2bf(v1.y); s[6] = f2bf(v1.z); s[7] = f2bf(v1.w);
        int row = flat >> 7;
        int col = flat & 127;
        *(bf16x8*)&dst[row * LDA + col] = s;
    }
}

__global__ __launch_bounds__(256) void zero_kernel(float* __restrict__ p, int n) {
    int i = blockIdx.x * 256 + threadIdx.x;
    if (i < n) p[i] = 0.0f;
}

// ---------------------------------------------------------------------------
// Fast path
// ---------------------------------------------------------------------------

// grid = 2048 x 256: one 16B chunk per thread for C and M; also zeros Lg.
__global__ __launch_bounds__(256) void convert_kernel(const float* __restrict__ ctx,
                                                      const float* __restrict__ mn,
                                                      short* __restrict__ Cbf,
                                                      short* __restrict__ Mbf,
                                                      float* __restrict__ Lg) {
    int tid = blockIdx.x * 256 + threadIdx.x;
    if (tid < BATCH * L_SEQ) Lg[tid] = 0.0f;
    const int half = BATCH * L_SEQ * DD / 8;  // chunks per tensor
    int id = tid;
    const float* src;
    short* dst;
    if (id < half) { src = ctx; dst = Cbf; }
    else           { id -= half; src = mn; dst = Mbf; }
    int row = id >> 4;
    int lc = id & 15;
    const float4* p = (const float4*)(src + ((size_t)row << 7) + lc * 8);
    float4 v0 = p[0];
    float4 v1 = p[1];
    bf16x8 s;
    s[0] = f2bf(v0.x); s[1] = f2bf(v0.y); s[2] = f2bf(v0.z); s[3] = f2bf(v0.w);
    s[4] = f2bf(v1.x); s[5] = f2bf(v1.y); s[6] = f2bf(v1.z); s[7] = f2bf(v1.w);
    int pc = (lc & 8) | ((lc ^ row) & 7);  // swizzle low 3 chunk bits by row&7
    *(bf16x8*)&dst[((size_t)row << 7) + pc * 8] = s;
}

// grid = 8 b * 32 ct * 4 mc = 1024 blocks, 256 thr (4 waves).
// LDS: Cs 16 KB + Ms dbuf 2x16 KB = 48 KB -> 3 blocks/CU (12 waves/CU).
// Per m-tile: ONE barrier; next-M DMA issued immediately after, flying across
// the whole compute body. E stored straight from registers (b64, swizzled).
__global__ __launch_bounds__(256, 3) void stats_kernel(const short* __restrict__ Cbf,
                                                       const short* __restrict__ Mbf,
                                                       float* __restrict__ Lg,
                                                       short* __restrict__ Eg) {
    __shared__ short Cs[64 * 128];
    __shared__ short Ms[2][64 * 128];

    int bid = blockIdx.x;
    int mc = bid & 3;
    int ct = (bid >> 2) & 31;
    int b  = bid >> 7;
    int t = threadIdx.x;
    int w = t >> 6;
    int l = t & 63;
    int a15 = l & 15;
    int q = l >> 4;
    int h = a15 & 7;

    {   // issue Cs (once) + Ms buf0 (m-tile 0): 4 DMA insts per wave each
        const short* gC = Cbf + ((size_t)(b * L_SEQ + ct * 64)) * DD;
        const short* gM = Mbf + ((size_t)(b * L_SEQ + mc * 512)) * DD;
        #pragma unroll
        for (int ii = 0; ii < 4; ++ii) {
            int inst = w * 4 + ii;
            gl2lds16(gC + inst * 512 + l * 8, Cs + inst * 512);
            gl2lds16(gM + inst * 512 + l * 8, Ms[0] + inst * 512);
        }
    }

    // Swizzled E chunk index for this lane (same for all g: m&7 == a15&7).
    int pc = ct * 8 + (((w * 2) + (q >> 1)) ^ h);
    int ecol = pc * 8 + (q & 1) * 4;

    float ls[4] = {0.f, 0.f, 0.f, 0.f};  // partial L for c = ct*64 + w*16 + q*4 + r

    for (int mt = 0; mt < 8; ++mt) {
        int bp = mt & 1;
        int m0 = mc * 512 + mt * 64;
        __syncthreads();  // drains DMA into Ms[bp] (and Cs on mt=0)

        if (mt < 7) {  // prefetch next tile into the other buffer; flies over compute
            const short* gM = Mbf + ((size_t)(b * L_SEQ + m0 + 64)) * DD;
            #pragma unroll
            for (int ii = 0; ii < 4; ++ii) {
                int inst = w * 4 + ii;
                gl2lds16(gM + inst * 512 + l * 8, Ms[bp ^ 1] + inst * 512);
            }
        }

        // D[c][m]: A = C rows (wave's 16 c), B = M rows (64 m). 16 MFMA/wave.
        f32x4 sacc[4] = {{0.f,0.f,0.f,0.f},{0.f,0.f,0.f,0.f},{0.f,0.f,0.f,0.f},{0.f,0.f,0.f,0.f}};
        #pragma unroll
        for (int ks = 0; ks < 4; ++ks) {
            int aoff = ((ks * 4 + q) ^ h) * 8;
            bf16x8 a = *(const bf16x8*)&Cs[(w * 16 + a15) * 128 + aoff];
            #pragma unroll
            for (int g = 0; g < 4; ++g) {
                bf16x8 bb = *(const bf16x8*)&Ms[bp][(g * 16 + a15) * 128 + aoff];
                sacc[g] = __builtin_amdgcn_mfma_f32_16x16x32_bf16(a, bb, sacc[g], 0, 0, 0);
            }
        }
        // D layout: row c = w*16 + q*4 + r, col m = g*16 + a15.
        // Lane's 4 regs = 4 CONSECUTIVE c at one m -> one b64 store per group.
        #pragma unroll
        for (int g = 0; g < 4; ++g) {
            bf16x4 pk;
            #pragma unroll
            for (int r = 0; r < 4; ++r) {
                float e = __expf(sacc[g][r] - SHIFT);
                ls[r] += e;
                pk[r] = f2bf(e);
            }
            int m = m0 + g * 16 + a15;
            *(bf16x4*)&Eg[((size_t)(b * L_SEQ + m)) * L_SEQ + ecol] = pk;
        }
    }

    // Reduce partial L over the 16 m-columns (a15 = lane bits 0..3), then atomics.
    #pragma unroll
    for (int r = 0; r < 4; ++r) {
        float v = ls[r];
        v += __shfl_xor(v, 1);
        v += __shfl_xor(v, 2);
        v += __shfl_xor(v, 4);
        v += __shfl_xor(v, 8);
        ls[r] = v;
    }
    if (a15 == 0) {
        int c = ct * 64 + w * 16 + q * 4;
        #pragma unroll
        for (int r = 0; r < 4; ++r)
            atomicAdd(&Lg[(size_t)b * L_SEQ + c + r], ls[r]);  // 4-way (mc) contention
    }
}

// grid = 8 b * 16 cc = 128 blocks, 256 thr. CtL[b][d][c] = bf16(C/L), swizzled by d&7.
__global__ __launch_bounds__(256) void prep_kernel(const float* __restrict__ ctx,
                                                   const float* __restrict__ Lg,
                                                   short* __restrict__ CtL) {
    __shared__ short Ts[128 * LDA];
    __shared__ float invLs[128];

    int b = blockIdx.x >> 4;
    int cc = blockIdx.x & 15;
    int t = threadIdx.x;

    if (t < 128) invLs[t] = 1.0f / Lg[(size_t)b * L_SEQ + cc * 128 + t];
    __syncthreads();

    const float* src = ctx + ((size_t)(b * L_SEQ + cc * 128)) * DD;
    #pragma unroll
    for (int i = 0; i < 8; ++i) {
        int flat = i * 2048 + t * 8;
        int r = flat >> 7;
        int c = flat & 127;
        const float4* p = (const float4*)(src + flat);
        float4 v0 = p[0];
        float4 v1 = p[1];
        float il = invLs[r];
        bf16x8 s;
        s[0] = f2bf(v0.x * il); s[1] = f2bf(v0.y * il); s[2] = f2bf(v0.z * il); s[3] = f2bf(v0.w * il);
        s[4] = f2bf(v1.x * il); s[5] = f2bf(v1.y * il); s[6] = f2bf(v1.z * il); s[7] = f2bf(v1.w * il);
        *(bf16x8*)&Ts[r * LDA + c] = s;
    }
    __syncthreads();

    int d = t >> 1;
    int ch = (t & 1) * 64;
    int key = d & 7;
    #pragma unroll
    for (int i = 0; i < 8; ++i) {
        int c = ch + i * 8;
        bf16x8 v;
        #pragma unroll
        for (int j = 0; j < 8; ++j) v[j] = Ts[(c + j) * LDA + d];
        int pc = cc * 16 + (ch >> 3) + (i ^ key);
        *(bf16x8*)&CtL[((size_t)(b * DD + d)) * L_SEQ + pc * 8] = v;
    }
}

// grid = 512 blocks, 256 thr. LDS 80 KB dbuf -> 2 blocks/CU.
// XCD-swizzled: b = bid & 7 so each XCD's L2 keeps one batch's CtL slice (512 KB).
// One barrier per c-step: drain buf, issue next buffer, compute current.
__global__ __launch_bounds__(256, 2) void attend_kernel(const short* __restrict__ Eg,
                                                        const short* __restrict__ CtL,
                                                        const float* __restrict__ mn,
                                                        float* __restrict__ out) {
    __shared__ short Et2[2][32 * 128];
    __shared__ short Ct2[2][128 * 128];

    int bid = blockIdx.x;
    int b = bid & 7;            // XCD-aware: same batch -> same XCD (L2 CtL reuse)
    int mtile = bid >> 3;       // 0..63
    int m0 = mtile * 32;
    int t = threadIdx.x;
    int w = t >> 6;
    int l = t & 63;
    int a15 = l & 15;
    int q = l >> 4;
    int h = a15 & 7;
    int lcc = l & 15;

    f32x4 acc[2][2] = {{{0.f,0.f,0.f,0.f},{0.f,0.f,0.f,0.f}},
                       {{0.f,0.f,0.f,0.f},{0.f,0.f,0.f,0.f}}};

    // issue buffer 0 (c-window 0): Et 2 insts/wave, Ct 8 insts/wave
    #pragma unroll
    for (int ii = 0; ii < 2; ++ii) {
        int inst = w * 2 + ii;
        gl2lds16(Eg + ((size_t)(b * L_SEQ + m0 + inst * 4 + q)) * L_SEQ + lcc * 8,
                 &Et2[0][inst * 512]);
    }
    #pragma unroll
    for (int ii = 0; ii < 8; ++ii) {
        int inst = w * 8 + ii;
        gl2lds16(CtL + ((size_t)(b * DD + inst * 4 + q)) * L_SEQ + lcc * 8,
                 &Ct2[0][inst * 512]);
    }

    for (int cs = 0; cs < 16; ++cs) {
        int bp = cs & 1;
        __syncthreads();  // drains loads into buf bp; buf bp^1 readers done last iter

        if (cs < 15) {  // issue next window into the other buffer; flies during compute
            int c0 = (cs + 1) * 128;
            #pragma unroll
            for (int ii = 0; ii < 2; ++ii) {
                int inst = w * 2 + ii;
                gl2lds16(Eg + ((size_t)(b * L_SEQ + m0 + inst * 4 + q)) * L_SEQ + c0 + lcc * 8,
                         &Et2[bp ^ 1][inst * 512]);
            }
            #pragma unroll
            for (int ii = 0; ii < 8; ++ii) {
                int inst = w * 8 + ii;
                gl2lds16(CtL + ((size_t)(b * DD + inst * 4 + q)) * L_SEQ + c0 + lcc * 8,
                         &Ct2[bp ^ 1][inst * 512]);
            }
        }

        const short* EtB = Et2[bp];
        const short* CtB = Ct2[bp];
        #pragma unroll
        for (int ks = 0; ks < 4; ++ks) {
            int aoff = ((ks * 4 + q) ^ h) * 8;
            bf16x8 a0 = *(const bf16x8*)&EtB[a15 * 128 + aoff];
            bf16x8 a1 = *(const bf16x8*)&EtB[(16 + a15) * 128 + aoff];
            bf16x8 b0 = *(const bf16x8*)&CtB[((w * 2 + 0) * 16 + a15) * 128 + aoff];
            bf16x8 b1 = *(const bf16x8*)&CtB[((w * 2 + 1) * 16 + a15) * 128 + aoff];
            acc[0][0] = __builtin_amdgcn_mfma_f32_16x16x32_bf16(a0, b0, acc[0][0], 0, 0, 0);
            acc[0][1] = __builtin_amdgcn_mfma_f32_16x16x32_bf16(a0, b1, acc[0][1], 0, 0, 0);
            acc[1][0] = __builtin_amdgcn_mfma_f32_16x16x32_bf16(a1, b0, acc[1][0], 0, 0, 0);
            acc[1][1] = __builtin_amdgcn_mfma_f32_16x16x32_bf16(a1, b1, acc[1][1], 0, 0, 0);
        }
    }

    // Epilogue: out = main(fp32) - O. D: col d = a15, row m = q*4+r.
    #pragma unroll
    for (int mg = 0; mg < 2; ++mg) {
        #pragma unroll
        for (int g = 0; g < 2; ++g) {
            int d = (w * 2 + g) * 16 + a15;
            #pragma unroll
            for (int r = 0; r < 4; ++r) {
                int m = m0 + mg * 16 + q * 4 + r;
                size_t idx = ((size_t)(b * L_SEQ + m)) * DD + d;
                out[idx] = mn[idx] - acc[mg][g][r];
            }
        }
    }
}

// ---------------------------------------------------------------------------
// Fallback path (round-2 kernels, tiny workspace)
// ---------------------------------------------------------------------------

__global__ __launch_bounds__(256, 4) void stats_fb(const float* __restrict__ ctx,
                                                   const float* __restrict__ mn,
                                                   float* __restrict__ Lg) {
    __shared__ short Cs[64 * LDA];
    __shared__ short Ms[64 * LDA];

    int bid = blockIdx.x;
    int mc = bid & 3;
    int ct = (bid >> 2) & 31;
    int b  = bid >> 7;
    int t = threadIdx.x;
    int w = t >> 6;
    int l = t & 63;
    int a15 = l & 15;
    int q = l >> 4;

    stage_tile<256>(Cs, ctx + ((size_t)b * L_SEQ + ct * 64) * DD, 64 * DD, t);

    float ls[4] = {0.f, 0.f, 0.f, 0.f};
    for (int mt = 0; mt < 8; ++mt) {
        __syncthreads();
        int m0 = (mc * 8 + mt) * 64;
        stage_tile<256>(Ms, mn + ((size_t)b * L_SEQ + m0) * DD, 64 * DD, t);
        __syncthreads();

        f32x4 acc[4] = {{0.f,0.f,0.f,0.f},{0.f,0.f,0.f,0.f},{0.f,0.f,0.f,0.f},{0.f,0.f,0.f,0.f}};
        #pragma unroll
        for (int ks = 0; ks < 4; ++ks) {
            int k0 = ks * 32 + q * 8;
            bf16x8 a = *(const bf16x8*)&Cs[(w * 16 + a15) * LDA + k0];
            #pragma unroll
            for (int g = 0; g < 4; ++g) {
                bf16x8 bb = *(const bf16x8*)&Ms[(g * 16 + a15) * LDA + k0];
                acc[g] = __builtin_amdgcn_mfma_f32_16x16x32_bf16(a, bb, acc[g], 0, 0, 0);
            }
        }
        #pragma unroll
        for (int g = 0; g < 4; ++g)
            #pragma unroll
            for (int r = 0; r < 4; ++r)
                ls[r] += __expf(acc[g][r] - SHIFT);
    }

    #pragma unroll
    for (int r = 0; r < 4; ++r) {
        float v = ls[r];
        v += __shfl_xor(v, 1);
        v += __shfl_xor(v, 2);
        v += __shfl_xor(v, 4);
        v += __shfl_xor(v, 8);
        ls[r] = v;
    }
    if (a15 == 0) {
        int c = ct * 64 + w * 16 + q * 4;
        #pragma unroll
        for (int r = 0; r < 4; ++r)
            atomicAdd(&Lg[(size_t)b * L_SEQ + c + r], ls[r]);
    }
}

__global__ __launch_bounds__(1024, 4) void attend_fb(const float* __restrict__ ctx,
                                                     const float* __restrict__ mn,
                                                     const float* __restrict__ Lg,
                                                     float* __restrict__ out) {
    __shared__ short Mt[64 * LDA];
    __shared__ short Cs[128 * LDA];
    __shared__ short Ct[128 * LDA];
    __shared__ short Ps[64 * LDA];
    __shared__ float invLs[128];

    int bid = blockIdx.x;
    int mtile = bid & 31;
    int b = bid >> 5;
    int m0 = mtile * 64;
    int t = threadIdx.x;
    int w = t >> 6;
    int l = t & 63;
    int a15 = l & 15;
    int q = l >> 4;
    int mg = w & 3;
    int pg = w >> 2;

    stage_tile<1024>(Mt, mn + ((size_t)b * L_SEQ + m0) * DD, 64 * DD, t);

    f32x4 oacc[2] = {{0.f,0.f,0.f,0.f},{0.f,0.f,0.f,0.f}};

    for (int cs = 0; cs < 16; ++cs) {
        int c0 = cs * 128;
        __syncthreads();
        stage_tile<1024>(Cs, ctx + ((size_t)b * L_SEQ + c0) * DD, 128 * DD, t);
        if (t < 128) invLs[t] = 1.0f / Lg[(size_t)b * L_SEQ + c0 + t];
        __syncthreads();

        {
            int cc = t & 127;
            int d0 = (t >> 7) * 16;
            #pragma unroll
            for (int hh = 0; hh < 2; ++hh) {
                bf16x8 v = *(const bf16x8*)&Cs[cc * LDA + d0 + hh * 8];
                #pragma unroll
                for (int j = 0; j < 8; ++j)
                    Ct[(d0 + hh * 8 + j) * LDA + cc] = v[j];
            }
        }

        f32x4 sacc[2] = {{0.f,0.f,0.f,0.f},{0.f,0.f,0.f,0.f}};
        #pragma unroll
        for (int ks = 0; ks < 4; ++ks) {
            int k0 = ks * 32 + q * 8;
            bf16x8 a = *(const bf16x8*)&Mt[(mg * 16 + a15) * LDA + k0];
            #pragma unroll
            for (int g = 0; g < 2; ++g) {
                bf16x8 bb = *(const bf16x8*)&Cs[((pg * 2 + g) * 16 + a15) * LDA + k0];
                sacc[g] = __builtin_amdgcn_mfma_f32_16x16x32_bf16(a, bb, sacc[g], 0, 0, 0);
            }
        }
        #pragma unroll
        for (int g = 0; g < 2; ++g) {
            int cl = (pg * 2 + g) * 16 + a15;
            float il = invLs[cl];
            #pragma unroll
            for (int r = 0; r < 4; ++r) {
                float p = __expf(sacc[g][r] - SHIFT) * il;
                Ps[(mg * 16 + q * 4 + r) * LDA + cl] = f2bf(p);
            }
        }
        __syncthreads();

        #pragma unroll
        for (int ks = 0; ks < 4; ++ks) {
            int k0 = ks * 32 + q * 8;
            bf16x8 a = *(const bf16x8*)&Ps[(mg * 16 + a15) * LDA + k0];
            #pragma unroll
            for (int g = 0; g < 2; ++g) {
                bf16x8 bb = *(const bf16x8*)&Ct[((pg * 2 + g) * 16 + a15) * LDA + k0];
                oacc[g] = __builtin_amdgcn_mfma_f32_16x16x32_bf16(a, bb, oacc[g], 0, 0, 0);
            }
        }
    }

    #pragma unroll
    for (int g = 0; g < 2; ++g) {
        int dl = (pg * 2 + g) * 16 + a15;
        #pragma unroll
        for (int r = 0; r < 4; ++r) {
            int ml = mg * 16 + q * 4 + r;
            size_t idx = ((size_t)b * L_SEQ + m0 + ml) * DD + dl;
            out[idx] = mn[idx] - oacc[g][r];
        }
    }
}

// ---------------------------------------------------------------------------

extern "C" void kernel_launch(void* const* d_in, const int* in_sizes, int n_in,
                              void* d_out, int out_size, void* d_ws, size_t ws_size,
                              hipStream_t stream) {
    const float* ctx = (const float*)d_in[0];  // (B, Lc, D)
    const float* mn  = (const float*)d_in[1];  // (B, Lm, D)
    float* out = (float*)d_out;                // (B, Lm, D)

    // Workspace: Lg 64 KB | Cbf 4 MB | Mbf 4 MB | CtL 4 MB | E 64 MB
    const size_t LG_BYTES = (size_t)BATCH * L_SEQ * sizeof(float);
    const size_t BF_BYTES = (size_t)BATCH * L_SEQ * DD * sizeof(short);
    const size_t E_BYTES  = (size_t)BATCH * L_SEQ * L_SEQ * sizeof(short);
    const size_t NEED = LG_BYTES + 3 * BF_BYTES + E_BYTES;

    float* Lg = (float*)d_ws;

    if (ws_size >= NEED) {
        short* Cbf = (short*)((char*)d_ws + LG_BYTES);
        short* Mbf = (short*)((char*)d_ws + LG_BYTES + BF_BYTES);
        short* CtL = (short*)((char*)d_ws + LG_BYTES + 2 * BF_BYTES);
        short* Eg  = (short*)((char*)d_ws + LG_BYTES + 3 * BF_BYTES);
        convert_kernel<<<2048, 256, 0, stream>>>(ctx, mn, Cbf, Mbf, Lg);
        stats_kernel<<<BATCH * 32 * 4, 256, 0, stream>>>(Cbf, Mbf, Lg, Eg);
        prep_kernel<<<BATCH * 16, 256, 0, stream>>>(ctx, Lg, CtL);
        attend_kernel<<<BATCH * 64, 256, 0, stream>>>(Eg, CtL, mn, out);
    } else {
        int nL = BATCH * L_SEQ;
        zero_kernel<<<(nL + 255) / 256, 256, 0, stream>>>(Lg, nL);
        stats_fb<<<BATCH * 32 * 4, 256, 0, stream>>>(ctx, mn, Lg);
        attend_fb<<<BATCH * 32, 1024, 0, stream>>>(ctx, mn, Lg, out);
    }
}

// Round 7
// 116.809 us; speedup vs baseline: 1.0453x; 1.0453x over previous
//
#include <hip/hip_runtime.h>

// AlignOnlySubLayer: out[b,m,d] = main[b,m,d] - sum_c softmax_m(C·M^T)[c,m] * C[c,d]
// B=8, Lc=Lm=2048, D=128, fp32 in/out.
// Round-7: R4-proven convert/prep/attend; stats = 128c x 512m block tile with
// DOUBLE-BUFFERED Ms (R5-proven hazard pattern: one barrier/step, DMA issued
// right after the barrier into the buffer NOT read this step).
//   convert: Cbf/Mbf = bf16(ctx/main) swizzled; Lg = 0
//   stats  : E[b,m,c] = bf16(exp(S-40)) direct reg->global (swizzled); L via atomics
//   prep   : CtL[b,d,c] = bf16(C[b,c,d]/L[b,c]) transposed + swizzled
//   attend : out = main - E · CtL  (dbuf async-staged MFMA GEMM, K=2048)
// Swizzle: 16B chunk pc = (lc&8)|((lc^row)&7) within 8-chunk (64-elem) groups;
// frag reads at ((ks*4+q) ^ (a15&7)) hit exactly 8 words/bank per ds_read_b128.

#define BATCH 8
#define L_SEQ 2048
#define DD 128
#define SHIFT 40.0f
#define LDA 136   // fallback/prep padded stride

typedef __attribute__((ext_vector_type(8))) short bf16x8;
typedef __attribute__((ext_vector_type(4))) short bf16x4;
typedef __attribute__((ext_vector_type(4))) float f32x4;

__device__ __forceinline__ short f2bf(float f) {
    unsigned u = __builtin_bit_cast(unsigned, f);
    return (short)((u + 0x8000u) >> 16);
}

// Async global->LDS, 16 B per lane. LDS dest = uniform base + lane*16.
__device__ __forceinline__ void gl2lds16(const short* g, short* l) {
    __builtin_amdgcn_global_load_lds(
        (const __attribute__((address_space(1))) unsigned int*)g,
        (__attribute__((address_space(3))) unsigned int*)l, 16, 0, 0);
}

// fp32 global (rows of 128) -> bf16 LDS tile, stride LDA (fallback path only).
template <int NT>
__device__ __forceinline__ void stage_tile(short* __restrict__ dst,
                                           const float* __restrict__ src,
                                           int nelts, int t) {
    for (int base = 0; base < nelts; base += NT * 8) {
        int flat = base + t * 8;
        const float4* p = (const float4*)(src + flat);
        float4 v0 = p[0];
        float4 v1 = p[1];
        bf16x8 s;
        s[0] = f2bf(v0.x); s[1] = f2bf(v0.y); s[2] = f2bf(v0.z); s[3] = f2bf(v0.w);
        s[4] = f2bf(v1.x); s[5] = f2bf(v1.y); s[6] = f2bf(v1.z); s[7] = f2bf(v1.w);
        int row = flat >> 7;
        int col = flat & 127;
        *(bf16x8*)&dst[row * LDA + col] = s;
    }
}

__global__ __launch_bounds__(256) void zero_kernel(float* __restrict__ p, int n) {
    int i = blockIdx.x * 256 + threadIdx.x;
    if (i < n) p[i] = 0.0f;
}

// ---------------------------------------------------------------------------
// Fast path
// ---------------------------------------------------------------------------

// grid = 2048 x 256: one 16B chunk per thread for C and M; also zeros Lg.
__global__ __launch_bounds__(256) void convert_kernel(const float* __restrict__ ctx,
                                                      const float* __restrict__ mn,
                                                      short* __restrict__ Cbf,
                                                      short* __restrict__ Mbf,
                                                      float* __restrict__ Lg) {
    int tid = blockIdx.x * 256 + threadIdx.x;
    if (tid < BATCH * L_SEQ) Lg[tid] = 0.0f;
    const int half = BATCH * L_SEQ * DD / 8;  // chunks per tensor
    int id = tid;
    const float* src;
    short* dst;
    if (id < half) { src = ctx; dst = Cbf; }
    else           { id -= half; src = mn; dst = Mbf; }
    int row = id >> 4;
    int lc = id & 15;
    const float4* p = (const float4*)(src + ((size_t)row << 7) + lc * 8);
    float4 v0 = p[0];
    float4 v1 = p[1];
    bf16x8 s;
    s[0] = f2bf(v0.x); s[1] = f2bf(v0.y); s[2] = f2bf(v0.z); s[3] = f2bf(v0.w);
    s[4] = f2bf(v1.x); s[5] = f2bf(v1.y); s[6] = f2bf(v1.z); s[7] = f2bf(v1.w);
    int pc = (lc & 8) | ((lc ^ row) & 7);  // swizzle low 3 chunk bits by row&7
    *(bf16x8*)&dst[((size_t)row << 7) + pc * 8] = s;
}

// grid = 8 b * 16 ct(128c) * 4 mc(512m) = 512 blocks, 256 thr (4 waves).
// LDS: Cs 32 KB + Ms dbuf 2x16 KB = 64 KB -> 2 blocks/CU (8 waves/CU).
// Per 64-m step: barrier (drains DMA into Ms[bp]) -> issue DMA into Ms[bp^1]
// -> 32 MFMA + 24 ds_read_b128 per wave -> E-store from registers.
// Safety: DMA never targets the buffer read this step; a wave reaching the
// next barrier has finished its reads of the buffer the next DMA overwrites.
__global__ __launch_bounds__(256, 2) void stats_kernel(const short* __restrict__ Cbf,
                                                       const short* __restrict__ Mbf,
                                                       float* __restrict__ Lg,
                                                       short* __restrict__ Eg) {
    __shared__ short Cs[128 * 128];
    __shared__ short Ms[2][64 * 128];

    int bid = blockIdx.x;
    int mc = bid & 3;
    int ct = (bid >> 2) & 15;
    int b  = bid >> 6;
    int t = threadIdx.x;
    int w = t >> 6;
    int l = t & 63;
    int a15 = l & 15;
    int q = l >> 4;
    int h = a15 & 7;
    int cw = (w & 1) * 64;   // wave c-offset within the 128-c tile
    int mw = (w >> 1) * 32;  // wave m-offset within the 64-m step

    {   // issue Cs (once, 8 insts/wave) + Ms buf0 (step 0, 4 insts/wave)
        const short* gC = Cbf + ((size_t)(b * L_SEQ + ct * 128)) * DD;
        const short* gM = Mbf + ((size_t)(b * L_SEQ + mc * 512)) * DD;
        #pragma unroll
        for (int ii = 0; ii < 8; ++ii) {
            int inst = w * 8 + ii;
            gl2lds16(gC + inst * 512 + l * 8, Cs + inst * 512);
        }
        #pragma unroll
        for (int ii = 0; ii < 4; ++ii) {
            int inst = w * 4 + ii;
            gl2lds16(gM + inst * 512 + l * 8, Ms[0] + inst * 512);
        }
    }

    float ls[4][4] = {};  // partial L for c = ct*128 + cw + i*16 + q*4 + r

    for (int ms = 0; ms < 8; ++ms) {
        int bp = ms & 1;
        __syncthreads();  // drains DMA into Ms[bp] (+Cs on ms=0)

        if (ms < 7) {  // prefetch next 64-m step into the OTHER buffer
            const short* gM = Mbf + ((size_t)(b * L_SEQ + mc * 512 + (ms + 1) * 64)) * DD;
            #pragma unroll
            for (int ii = 0; ii < 4; ++ii) {
                int inst = w * 4 + ii;
                gl2lds16(gM + inst * 512 + l * 8, Ms[bp ^ 1] + inst * 512);
            }
        }

        // D[c][m]: A = C rows (wave's 64 c), B = M rows (wave's 32 m).
        f32x4 acc[4][2];
        #pragma unroll
        for (int i = 0; i < 4; ++i)
            #pragma unroll
            for (int j = 0; j < 2; ++j) {
                f32x4 z = {0.f, 0.f, 0.f, 0.f};
                acc[i][j] = z;
            }
        #pragma unroll
        for (int ks = 0; ks < 4; ++ks) {
            int aoff = ((ks * 4 + q) ^ h) * 8;
            bf16x8 af[4], bv[2];
            #pragma unroll
            for (int i = 0; i < 4; ++i)
                af[i] = *(const bf16x8*)&Cs[(cw + i * 16 + a15) * 128 + aoff];
            #pragma unroll
            for (int j = 0; j < 2; ++j)
                bv[j] = *(const bf16x8*)&Ms[bp][(mw + j * 16 + a15) * 128 + aoff];
            #pragma unroll
            for (int i = 0; i < 4; ++i)
                #pragma unroll
                for (int j = 0; j < 2; ++j)
                    acc[i][j] = __builtin_amdgcn_mfma_f32_16x16x32_bf16(af[i], bv[j], acc[i][j], 0, 0, 0);
        }

        // E store straight from registers (b64, swizzled). D layout: row c = q*4+r
        // (4 consecutive c per lane), col m = a15.
        #pragma unroll
        for (int j = 0; j < 2; ++j) {
            int m = mc * 512 + ms * 64 + mw + j * 16 + a15;
            size_t rowb = ((size_t)(b * L_SEQ + m)) * L_SEQ;
            #pragma unroll
            for (int i = 0; i < 4; ++i) {
                bf16x4 pk;
                #pragma unroll
                for (int r = 0; r < 4; ++r) {
                    float e = __expf(acc[i][j][r] - SHIFT);
                    ls[i][r] += e;
                    pk[r] = f2bf(e);
                }
                int cq = ct * 128 + cw + i * 16 + q * 4;
                int chunk = cq >> 3;
                int pcc = (chunk & ~7) | ((chunk ^ m) & 7);
                *(bf16x4*)&Eg[rowb + pcc * 8 + (cq & 7)] = pk;
            }
        }
    }

    // Reduce partial L over the 16 m-columns (lane bits 0..3), then atomics.
    #pragma unroll
    for (int i = 0; i < 4; ++i)
        #pragma unroll
        for (int r = 0; r < 4; ++r) {
            float v = ls[i][r];
            v += __shfl_xor(v, 1);
            v += __shfl_xor(v, 2);
            v += __shfl_xor(v, 4);
            v += __shfl_xor(v, 8);
            ls[i][r] = v;
        }
    if (a15 == 0) {
        #pragma unroll
        for (int i = 0; i < 4; ++i) {
            int c = ct * 128 + cw + i * 16 + q * 4;
            #pragma unroll
            for (int r = 0; r < 4; ++r)
                atomicAdd(&Lg[(size_t)b * L_SEQ + c + r], ls[i][r]);  // 8-way total contention
        }
    }
}

// grid = 8 b * 16 cc = 128 blocks, 256 thr. CtL[b][d][c] = bf16(C/L), swizzled by d&7.
__global__ __launch_bounds__(256) void prep_kernel(const float* __restrict__ ctx,
                                                   const float* __restrict__ Lg,
                                                   short* __restrict__ CtL) {
    __shared__ short Ts[128 * LDA];
    __shared__ float invLs[128];

    int b = blockIdx.x >> 4;
    int cc = blockIdx.x & 15;
    int t = threadIdx.x;

    if (t < 128) invLs[t] = 1.0f / Lg[(size_t)b * L_SEQ + cc * 128 + t];
    __syncthreads();

    const float* src = ctx + ((size_t)(b * L_SEQ + cc * 128)) * DD;
    #pragma unroll
    for (int i = 0; i < 8; ++i) {
        int flat = i * 2048 + t * 8;
        int r = flat >> 7;
        int c = flat & 127;
        const float4* p = (const float4*)(src + flat);
        float4 v0 = p[0];
        float4 v1 = p[1];
        float il = invLs[r];
        bf16x8 s;
        s[0] = f2bf(v0.x * il); s[1] = f2bf(v0.y * il); s[2] = f2bf(v0.z * il); s[3] = f2bf(v0.w * il);
        s[4] = f2bf(v1.x * il); s[5] = f2bf(v1.y * il); s[6] = f2bf(v1.z * il); s[7] = f2bf(v1.w * il);
        *(bf16x8*)&Ts[r * LDA + c] = s;
    }
    __syncthreads();

    int d = t >> 1;
    int ch = (t & 1) * 64;
    int key = d & 7;
    #pragma unroll
    for (int i = 0; i < 8; ++i) {
        int c = ch + i * 8;
        bf16x8 v;
        #pragma unroll
        for (int j = 0; j < 8; ++j) v[j] = Ts[(c + j) * LDA + d];
        int pc = cc * 16 + (ch >> 3) + (i ^ key);
        *(bf16x8*)&CtL[((size_t)(b * DD + d)) * L_SEQ + pc * 8] = v;
    }
}

// grid = 512 blocks, 256 thr. LDS 80 KB dbuf -> 2 blocks/CU. (R4-proven form.)
__global__ __launch_bounds__(256, 2) void attend_kernel(const short* __restrict__ Eg,
                                                        const short* __restrict__ CtL,
                                                        const float* __restrict__ mn,
                                                        float* __restrict__ out) {
    __shared__ short Et2[2][32 * 128];
    __shared__ short Ct2[2][128 * 128];

    int bid = blockIdx.x;
    int mtile = bid & 63;
    int b = bid >> 6;
    int m0 = mtile * 32;
    int t = threadIdx.x;
    int w = t >> 6;
    int l = t & 63;
    int a15 = l & 15;
    int q = l >> 4;
    int h = a15 & 7;
    int lcc = l & 15;

    f32x4 acc[2][2] = {{{0.f,0.f,0.f,0.f},{0.f,0.f,0.f,0.f}},
                       {{0.f,0.f,0.f,0.f},{0.f,0.f,0.f,0.f}}};

    // issue buffer 0 (c-window 0): Et 2 insts/wave, Ct 8 insts/wave
    #pragma unroll
    for (int ii = 0; ii < 2; ++ii) {
        int inst = w * 2 + ii;
        gl2lds16(Eg + ((size_t)(b * L_SEQ + m0 + inst * 4 + q)) * L_SEQ + lcc * 8,
                 &Et2[0][inst * 512]);
    }
    #pragma unroll
    for (int ii = 0; ii < 8; ++ii) {
        int inst = w * 8 + ii;
        gl2lds16(CtL + ((size_t)(b * DD + inst * 4 + q)) * L_SEQ + lcc * 8,
                 &Ct2[0][inst * 512]);
    }

    for (int cs = 0; cs < 16; ++cs) {
        int bp = cs & 1;
        __syncthreads();  // drains loads into buf bp; buf bp^1 readers done last iter

        if (cs < 15) {  // issue next window into the other buffer; flies during compute
            int c0 = (cs + 1) * 128;
            #pragma unroll
            for (int ii = 0; ii < 2; ++ii) {
                int inst = w * 2 + ii;
                gl2lds16(Eg + ((size_t)(b * L_SEQ + m0 + inst * 4 + q)) * L_SEQ + c0 + lcc * 8,
                         &Et2[bp ^ 1][inst * 512]);
            }
            #pragma unroll
            for (int ii = 0; ii < 8; ++ii) {
                int inst = w * 8 + ii;
                gl2lds16(CtL + ((size_t)(b * DD + inst * 4 + q)) * L_SEQ + c0 + lcc * 8,
                         &Ct2[bp ^ 1][inst * 512]);
            }
        }

        const short* EtB = Et2[bp];
        const short* CtB = Ct2[bp];
        #pragma unroll
        for (int ks = 0; ks < 4; ++ks) {
            int aoff = ((ks * 4 + q) ^ h) * 8;
            bf16x8 a0 = *(const bf16x8*)&EtB[a15 * 128 + aoff];
            bf16x8 a1 = *(const bf16x8*)&EtB[(16 + a15) * 128 + aoff];
            bf16x8 b0 = *(const bf16x8*)&CtB[((w * 2 + 0) * 16 + a15) * 128 + aoff];
            bf16x8 b1 = *(const bf16x8*)&CtB[((w * 2 + 1) * 16 + a15) * 128 + aoff];
            acc[0][0] = __builtin_amdgcn_mfma_f32_16x16x32_bf16(a0, b0, acc[0][0], 0, 0, 0);
            acc[0][1] = __builtin_amdgcn_mfma_f32_16x16x32_bf16(a0, b1, acc[0][1], 0, 0, 0);
            acc[1][0] = __builtin_amdgcn_mfma_f32_16x16x32_bf16(a1, b0, acc[1][0], 0, 0, 0);
            acc[1][1] = __builtin_amdgcn_mfma_f32_16x16x32_bf16(a1, b1, acc[1][1], 0, 0, 0);
        }
    }

    // Epilogue: out = main(fp32) - O. D: col d = a15, row m = q*4+r.
    #pragma unroll
    for (int mg = 0; mg < 2; ++mg) {
        #pragma unroll
        for (int g = 0; g < 2; ++g) {
            int d = (w * 2 + g) * 16 + a15;
            #pragma unroll
            for (int r = 0; r < 4; ++r) {
                int m = m0 + mg * 16 + q * 4 + r;
                size_t idx = ((size_t)(b * L_SEQ + m)) * DD + d;
                out[idx] = mn[idx] - acc[mg][g][r];
            }
        }
    }
}

// ---------------------------------------------------------------------------
// Fallback path (round-2 kernels, tiny workspace)
// ---------------------------------------------------------------------------

__global__ __launch_bounds__(256, 4) void stats_fb(const float* __restrict__ ctx,
                                                   const float* __restrict__ mn,
                                                   float* __restrict__ Lg) {
    __shared__ short Cs[64 * LDA];
    __shared__ short Ms[64 * LDA];

    int bid = blockIdx.x;
    int mc = bid & 3;
    int ct = (bid >> 2) & 31;
    int b  = bid >> 7;
    int t = threadIdx.x;
    int w = t >> 6;
    int l = t & 63;
    int a15 = l & 15;
    int q = l >> 4;

    stage_tile<256>(Cs, ctx + ((size_t)b * L_SEQ + ct * 64) * DD, 64 * DD, t);

    float ls[4] = {0.f, 0.f, 0.f, 0.f};
    for (int mt = 0; mt < 8; ++mt) {
        __syncthreads();
        int m0 = (mc * 8 + mt) * 64;
        stage_tile<256>(Ms, mn + ((size_t)b * L_SEQ + m0) * DD, 64 * DD, t);
        __syncthreads();

        f32x4 acc[4] = {{0.f,0.f,0.f,0.f},{0.f,0.f,0.f,0.f},{0.f,0.f,0.f,0.f},{0.f,0.f,0.f,0.f}};
        #pragma unroll
        for (int ks = 0; ks < 4; ++ks) {
            int k0 = ks * 32 + q * 8;
            bf16x8 a = *(const bf16x8*)&Cs[(w * 16 + a15) * LDA + k0];
            #pragma unroll
            for (int g = 0; g < 4; ++g) {
                bf16x8 bb = *(const bf16x8*)&Ms[(g * 16 + a15) * LDA + k0];
                acc[g] = __builtin_amdgcn_mfma_f32_16x16x32_bf16(a, bb, acc[g], 0, 0, 0);
            }
        }
        #pragma unroll
        for (int g = 0; g < 4; ++g)
            #pragma unroll
            for (int r = 0; r < 4; ++r)
                ls[r] += __expf(acc[g][r] - SHIFT);
    }

    #pragma unroll
    for (int r = 0; r < 4; ++r) {
        float v = ls[r];
        v += __shfl_xor(v, 1);
        v += __shfl_xor(v, 2);
        v += __shfl_xor(v, 4);
        v += __shfl_xor(v, 8);
        ls[r] = v;
    }
    if (a15 == 0) {
        int c = ct * 64 + w * 16 + q * 4;
        #pragma unroll
        for (int r = 0; r < 4; ++r)
            atomicAdd(&Lg[(size_t)b * L_SEQ + c + r], ls[r]);
    }
}

__global__ __launch_bounds__(1024, 4) void attend_fb(const float* __restrict__ ctx,
                                                     const float* __restrict__ mn,
                                                     const float* __restrict__ Lg,
                                                     float* __restrict__ out) {
    __shared__ short Mt[64 * LDA];
    __shared__ short Cs[128 * LDA];
    __shared__ short Ct[128 * LDA];
    __shared__ short Ps[64 * LDA];
    __shared__ float invLs[128];

    int bid = blockIdx.x;
    int mtile = bid & 31;
    int b = bid >> 5;
    int m0 = mtile * 64;
    int t = threadIdx.x;
    int w = t >> 6;
    int l = t & 63;
    int a15 = l & 15;
    int q = l >> 4;
    int mg = w & 3;
    int pg = w >> 2;

    stage_tile<1024>(Mt, mn + ((size_t)b * L_SEQ + m0) * DD, 64 * DD, t);

    f32x4 oacc[2] = {{0.f,0.f,0.f,0.f},{0.f,0.f,0.f,0.f}};

    for (int cs = 0; cs < 16; ++cs) {
        int c0 = cs * 128;
        __syncthreads();
        stage_tile<1024>(Cs, ctx + ((size_t)b * L_SEQ + c0) * DD, 128 * DD, t);
        if (t < 128) invLs[t] = 1.0f / Lg[(size_t)b * L_SEQ + c0 + t];
        __syncthreads();

        {
            int cc = t & 127;
            int d0 = (t >> 7) * 16;
            #pragma unroll
            for (int hh = 0; hh < 2; ++hh) {
                bf16x8 v = *(const bf16x8*)&Cs[cc * LDA + d0 + hh * 8];
                #pragma unroll
                for (int j = 0; j < 8; ++j)
                    Ct[(d0 + hh * 8 + j) * LDA + cc] = v[j];
            }
        }

        f32x4 sacc[2] = {{0.f,0.f,0.f,0.f},{0.f,0.f,0.f,0.f}};
        #pragma unroll
        for (int ks = 0; ks < 4; ++ks) {
            int k0 = ks * 32 + q * 8;
            bf16x8 a = *(const bf16x8*)&Mt[(mg * 16 + a15) * LDA + k0];
            #pragma unroll
            for (int g = 0; g < 2; ++g) {
                bf16x8 bb = *(const bf16x8*)&Cs[((pg * 2 + g) * 16 + a15) * LDA + k0];
                sacc[g] = __builtin_amdgcn_mfma_f32_16x16x32_bf16(a, bb, sacc[g], 0, 0, 0);
            }
        }
        #pragma unroll
        for (int g = 0; g < 2; ++g) {
            int cl = (pg * 2 + g) * 16 + a15;
            float il = invLs[cl];
            #pragma unroll
            for (int r = 0; r < 4; ++r) {
                float p = __expf(sacc[g][r] - SHIFT) * il;
                Ps[(mg * 16 + q * 4 + r) * LDA + cl] = f2bf(p);
            }
        }
        __syncthreads();

        #pragma unroll
        for (int ks = 0; ks < 4; ++ks) {
            int k0 = ks * 32 + q * 8;
            bf16x8 a = *(const bf16x8*)&Ps[(mg * 16 + a15) * LDA + k0];
            #pragma unroll
            for (int g = 0; g < 2; ++g) {
                bf16x8 bb = *(const bf16x8*)&Ct[((pg * 2 + g) * 16 + a15) * LDA + k0];
                oacc[g] = __builtin_amdgcn_mfma_f32_16x16x32_bf16(a, bb, oacc[g], 0, 0, 0);
            }
        }
    }

    #pragma unroll
    for (int g = 0; g < 2; ++g) {
        int dl = (pg * 2 + g) * 16 + a15;
        #pragma unroll
        for (int r = 0; r < 4; ++r) {
            int ml = mg * 16 + q * 4 + r;
            size_t idx = ((size_t)b * L_SEQ + m0 + ml) * DD + dl;
            out[idx] = mn[idx] - oacc[g][r];
        }
    }
}

// ---------------------------------------------------------------------------

extern "C" void kernel_launch(void* const* d_in, const int* in_sizes, int n_in,
                              void* d_out, int out_size, void* d_ws, size_t ws_size,
                              hipStream_t stream) {
    const float* ctx = (const float*)d_in[0];  // (B, Lc, D)
    const float* mn  = (const float*)d_in[1];  // (B, Lm, D)
    float* out = (float*)d_out;                // (B, Lm, D)

    // Workspace: Lg 64 KB | Cbf 4 MB | Mbf 4 MB | CtL 4 MB | E 67 MB
    const size_t LG_BYTES = (size_t)BATCH * L_SEQ * sizeof(float);
    const size_t BF_BYTES = (size_t)BATCH * L_SEQ * DD * sizeof(short);
    const size_t E_BYTES  = (size_t)BATCH * L_SEQ * L_SEQ * sizeof(short);
    const size_t NEED = LG_BYTES + 3 * BF_BYTES + E_BYTES;

    float* Lg = (float*)d_ws;

    if (ws_size >= NEED) {
        short* Cbf = (short*)((char*)d_ws + LG_BYTES);
        short* Mbf = (short*)((char*)d_ws + LG_BYTES + BF_BYTES);
        short* CtL = (short*)((char*)d_ws + LG_BYTES + 2 * BF_BYTES);
        short* Eg  = (short*)((char*)d_ws + LG_BYTES + 3 * BF_BYTES);
        convert_kernel<<<2048, 256, 0, stream>>>(ctx, mn, Cbf, Mbf, Lg);
        stats_kernel<<<BATCH * 16 * 4, 256, 0, stream>>>(Cbf, Mbf, Lg, Eg);
        prep_kernel<<<BATCH * 16, 256, 0, stream>>>(ctx, Lg, CtL);
        attend_kernel<<<BATCH * 64, 256, 0, stream>>>(Eg, CtL, mn, out);
    } else {
        int nL = BATCH * L_SEQ;
        zero_kernel<<<(nL + 255) / 256, 256, 0, stream>>>(Lg, nL);
        stats_fb<<<BATCH * 32 * 4, 256, 0, stream>>>(ctx, mn, Lg);
        attend_fb<<<BATCH * 32, 1024, 0, stream>>>(ctx, mn, Lg, out);
    }
}

// Round 8
// 115.257 us; speedup vs baseline: 1.0594x; 1.0135x over previous
//
#include <hip/hip_runtime.h>

// AlignOnlySubLayer: out[b,m,d] = main[b,m,d] - sum_c softmax_m(C·M^T)[c,m] * C[c,d]
// B=8, Lc=Lm=2048, D=128, fp32 in/out.
// Round-8: identical to passing R7 except stats hoists its invariant C-tile
// MFMA A-fragments into registers once (removes 16 of 24 ds_read_b128 per
// wave-step; stats was LDS-read-bound: 2300 LDS cyc vs 1240 MFMA cyc per CU-step).
//   convert: Cbf/Mbf = bf16(ctx/main) swizzled; Lg = 0
//   stats  : E[b,m,c] = bf16(exp(S-40)) direct reg->global (swizzled); L via atomics
//   prep   : CtL[b,d,c] = bf16(C[b,c,d]/L[b,c]) transposed + swizzled
//   attend : out = main - E · CtL  (dbuf async-staged MFMA GEMM, K=2048)
// Swizzle: 16B chunk pc = (lc&8)|((lc^row)&7) within 8-chunk (64-elem) groups;
// frag reads at ((ks*4+q) ^ (a15&7)) hit exactly 8 words/bank per ds_read_b128.

#define BATCH 8
#define L_SEQ 2048
#define DD 128
#define SHIFT 40.0f
#define LDA 136   // fallback/prep padded stride

typedef __attribute__((ext_vector_type(8))) short bf16x8;
typedef __attribute__((ext_vector_type(4))) short bf16x4;
typedef __attribute__((ext_vector_type(4))) float f32x4;

__device__ __forceinline__ short f2bf(float f) {
    unsigned u = __builtin_bit_cast(unsigned, f);
    return (short)((u + 0x8000u) >> 16);
}

// Async global->LDS, 16 B per lane. LDS dest = uniform base + lane*16.
__device__ __forceinline__ void gl2lds16(const short* g, short* l) {
    __builtin_amdgcn_global_load_lds(
        (const __attribute__((address_space(1))) unsigned int*)g,
        (__attribute__((address_space(3))) unsigned int*)l, 16, 0, 0);
}

// fp32 global (rows of 128) -> bf16 LDS tile, stride LDA (fallback path only).
template <int NT>
__device__ __forceinline__ void stage_tile(short* __restrict__ dst,
                                           const float* __restrict__ src,
                                           int nelts, int t) {
    for (int base = 0; base < nelts; base += NT * 8) {
        int flat = base + t * 8;
        const float4* p = (const float4*)(src + flat);
        float4 v0 = p[0];
        float4 v1 = p[1];
        bf16x8 s;
        s[0] = f2bf(v0.x); s[1] = f2bf(v0.y); s[2] = f2bf(v0.z); s[3] = f2bf(v0.w);
        s[4] = f2bf(v1.x); s[5] = f2bf(v1.y); s[6] = f2bf(v1.z); s[7] = f2bf(v1.w);
        int row = flat >> 7;
        int col = flat & 127;
        *(bf16x8*)&dst[row * LDA + col] = s;
    }
}

__global__ __launch_bounds__(256) void zero_kernel(float* __restrict__ p, int n) {
    int i = blockIdx.x * 256 + threadIdx.x;
    if (i < n) p[i] = 0.0f;
}

// ---------------------------------------------------------------------------
// Fast path
// ---------------------------------------------------------------------------

// grid = 2048 x 256: one 16B chunk per thread for C and M; also zeros Lg.
__global__ __launch_bounds__(256) void convert_kernel(const float* __restrict__ ctx,
                                                      const float* __restrict__ mn,
                                                      short* __restrict__ Cbf,
                                                      short* __restrict__ Mbf,
                                                      float* __restrict__ Lg) {
    int tid = blockIdx.x * 256 + threadIdx.x;
    if (tid < BATCH * L_SEQ) Lg[tid] = 0.0f;
    const int half = BATCH * L_SEQ * DD / 8;  // chunks per tensor
    int id = tid;
    const float* src;
    short* dst;
    if (id < half) { src = ctx; dst = Cbf; }
    else           { id -= half; src = mn; dst = Mbf; }
    int row = id >> 4;
    int lc = id & 15;
    const float4* p = (const float4*)(src + ((size_t)row << 7) + lc * 8);
    float4 v0 = p[0];
    float4 v1 = p[1];
    bf16x8 s;
    s[0] = f2bf(v0.x); s[1] = f2bf(v0.y); s[2] = f2bf(v0.z); s[3] = f2bf(v0.w);
    s[4] = f2bf(v1.x); s[5] = f2bf(v1.y); s[6] = f2bf(v1.z); s[7] = f2bf(v1.w);
    int pc = (lc & 8) | ((lc ^ row) & 7);  // swizzle low 3 chunk bits by row&7
    *(bf16x8*)&dst[((size_t)row << 7) + pc * 8] = s;
}

// grid = 8 b * 16 ct(128c) * 4 mc(512m) = 512 blocks, 256 thr (4 waves).
// LDS: Cs 32 KB + Ms dbuf 2x16 KB = 64 KB -> 2 blocks/CU (8 waves/CU).
// A-fragments of the invariant C tile are hoisted into registers ONCE
// (af[4][4], 64 VGPRs) -> per 64-m step only 8 ds_read_b128 + 32 MFMA.
// Dbuf hazard pattern (R5/R7-proven): barrier drains DMA into Ms[bp]; next
// DMA targets Ms[bp^1], whose readers all passed the barrier already.
__global__ __launch_bounds__(256, 2) void stats_kernel(const short* __restrict__ Cbf,
                                                       const short* __restrict__ Mbf,
                                                       float* __restrict__ Lg,
                                                       short* __restrict__ Eg) {
    __shared__ short Cs[128 * 128];
    __shared__ short Ms[2][64 * 128];

    int bid = blockIdx.x;
    int mc = bid & 3;
    int ct = (bid >> 2) & 15;
    int b  = bid >> 6;
    int t = threadIdx.x;
    int w = t >> 6;
    int l = t & 63;
    int a15 = l & 15;
    int q = l >> 4;
    int h = a15 & 7;
    int cw = (w & 1) * 64;   // wave c-offset within the 128-c tile
    int mw = (w >> 1) * 32;  // wave m-offset within the 64-m step

    {   // issue Cs (once, 8 insts/wave) + Ms buf0 (step 0, 4 insts/wave)
        const short* gC = Cbf + ((size_t)(b * L_SEQ + ct * 128)) * DD;
        const short* gM = Mbf + ((size_t)(b * L_SEQ + mc * 512)) * DD;
        #pragma unroll
        for (int ii = 0; ii < 8; ++ii) {
            int inst = w * 8 + ii;
            gl2lds16(gC + inst * 512 + l * 8, Cs + inst * 512);
        }
        #pragma unroll
        for (int ii = 0; ii < 4; ++ii) {
            int inst = w * 4 + ii;
            gl2lds16(gM + inst * 512 + l * 8, Ms[0] + inst * 512);
        }
    }

    __syncthreads();  // drains Cs + Ms[0]

    {   // prefetch step-1 M into Ms[1]; disjoint from Cs/Ms[0], flies over hoist
        const short* gM = Mbf + ((size_t)(b * L_SEQ + mc * 512 + 64)) * DD;
        #pragma unroll
        for (int ii = 0; ii < 4; ++ii) {
            int inst = w * 4 + ii;
            gl2lds16(gM + inst * 512 + l * 8, Ms[1] + inst * 512);
        }
    }

    // Hoist invariant C A-fragments: af[ks][i], 16 ds_read_b128 -> 64 VGPRs.
    bf16x8 af[4][4];
    #pragma unroll
    for (int ks = 0; ks < 4; ++ks) {
        int aoff = ((ks * 4 + q) ^ h) * 8;
        #pragma unroll
        for (int i = 0; i < 4; ++i)
            af[ks][i] = *(const bf16x8*)&Cs[(cw + i * 16 + a15) * 128 + aoff];
    }

    float ls[4][4] = {};  // partial L for c = ct*128 + cw + i*16 + q*4 + r

    for (int ms = 0; ms < 8; ++ms) {
        int bp = ms & 1;
        if (ms > 0) {
            __syncthreads();  // drains DMA into Ms[bp] (issued at ms-1)
            if (ms < 7) {     // prefetch next step into the OTHER buffer
                const short* gM = Mbf + ((size_t)(b * L_SEQ + mc * 512 + (ms + 1) * 64)) * DD;
                #pragma unroll
                for (int ii = 0; ii < 4; ++ii) {
                    int inst = w * 4 + ii;
                    gl2lds16(gM + inst * 512 + l * 8, Ms[bp ^ 1] + inst * 512);
                }
            }
        }

        // D[c][m]: A = hoisted C frags (wave's 64 c), B = M rows (wave's 32 m).
        f32x4 acc[4][2];
        #pragma unroll
        for (int i = 0; i < 4; ++i)
            #pragma unroll
            for (int j = 0; j < 2; ++j) {
                f32x4 z = {0.f, 0.f, 0.f, 0.f};
                acc[i][j] = z;
            }
        #pragma unroll
        for (int ks = 0; ks < 4; ++ks) {
            int aoff = ((ks * 4 + q) ^ h) * 8;
            bf16x8 bv[2];
            #pragma unroll
            for (int j = 0; j < 2; ++j)
                bv[j] = *(const bf16x8*)&Ms[bp][(mw + j * 16 + a15) * 128 + aoff];
            #pragma unroll
            for (int i = 0; i < 4; ++i)
                #pragma unroll
                for (int j = 0; j < 2; ++j)
                    acc[i][j] = __builtin_amdgcn_mfma_f32_16x16x32_bf16(af[ks][i], bv[j], acc[i][j], 0, 0, 0);
        }

        // E store straight from registers (b64, swizzled). D layout: row c = q*4+r
        // (4 consecutive c per lane), col m = a15.
        #pragma unroll
        for (int j = 0; j < 2; ++j) {
            int m = mc * 512 + ms * 64 + mw + j * 16 + a15;
            size_t rowb = ((size_t)(b * L_SEQ + m)) * L_SEQ;
            #pragma unroll
            for (int i = 0; i < 4; ++i) {
                bf16x4 pk;
                #pragma unroll
                for (int r = 0; r < 4; ++r) {
                    float e = __expf(acc[i][j][r] - SHIFT);
                    ls[i][r] += e;
                    pk[r] = f2bf(e);
                }
                int cq = ct * 128 + cw + i * 16 + q * 4;
                int chunk = cq >> 3;
                int pcc = (chunk & ~7) | ((chunk ^ m) & 7);
                *(bf16x4*)&Eg[rowb + pcc * 8 + (cq & 7)] = pk;
            }
        }
    }

    // Reduce partial L over the 16 m-columns (lane bits 0..3), then atomics.
    #pragma unroll
    for (int i = 0; i < 4; ++i)
        #pragma unroll
        for (int r = 0; r < 4; ++r) {
            float v = ls[i][r];
            v += __shfl_xor(v, 1);
            v += __shfl_xor(v, 2);
            v += __shfl_xor(v, 4);
            v += __shfl_xor(v, 8);
            ls[i][r] = v;
        }
    if (a15 == 0) {
        #pragma unroll
        for (int i = 0; i < 4; ++i) {
            int c = ct * 128 + cw + i * 16 + q * 4;
            #pragma unroll
            for (int r = 0; r < 4; ++r)
                atomicAdd(&Lg[(size_t)b * L_SEQ + c + r], ls[i][r]);  // 8-way total contention
        }
    }
}

// grid = 8 b * 16 cc = 128 blocks, 256 thr. CtL[b][d][c] = bf16(C/L), swizzled by d&7.
__global__ __launch_bounds__(256) void prep_kernel(const float* __restrict__ ctx,
                                                   const float* __restrict__ Lg,
                                                   short* __restrict__ CtL) {
    __shared__ short Ts[128 * LDA];
    __shared__ float invLs[128];

    int b = blockIdx.x >> 4;
    int cc = blockIdx.x & 15;
    int t = threadIdx.x;

    if (t < 128) invLs[t] = 1.0f / Lg[(size_t)b * L_SEQ + cc * 128 + t];
    __syncthreads();

    const float* src = ctx + ((size_t)(b * L_SEQ + cc * 128)) * DD;
    #pragma unroll
    for (int i = 0; i < 8; ++i) {
        int flat = i * 2048 + t * 8;
        int r = flat >> 7;
        int c = flat & 127;
        const float4* p = (const float4*)(src + flat);
        float4 v0 = p[0];
        float4 v1 = p[1];
        float il = invLs[r];
        bf16x8 s;
        s[0] = f2bf(v0.x * il); s[1] = f2bf(v0.y * il); s[2] = f2bf(v0.z * il); s[3] = f2bf(v0.w * il);
        s[4] = f2bf(v1.x * il); s[5] = f2bf(v1.y * il); s[6] = f2bf(v1.z * il); s[7] = f2bf(v1.w * il);
        *(bf16x8*)&Ts[r * LDA + c] = s;
    }
    __syncthreads();

    int d = t >> 1;
    int ch = (t & 1) * 64;
    int key = d & 7;
    #pragma unroll
    for (int i = 0; i < 8; ++i) {
        int c = ch + i * 8;
        bf16x8 v;
        #pragma unroll
        for (int j = 0; j < 8; ++j) v[j] = Ts[(c + j) * LDA + d];
        int pc = cc * 16 + (ch >> 3) + (i ^ key);
        *(bf16x8*)&CtL[((size_t)(b * DD + d)) * L_SEQ + pc * 8] = v;
    }
}

// grid = 512 blocks, 256 thr. LDS 80 KB dbuf -> 2 blocks/CU. (R4-proven form.)
__global__ __launch_bounds__(256, 2) void attend_kernel(const short* __restrict__ Eg,
                                                        const short* __restrict__ CtL,
                                                        const float* __restrict__ mn,
                                                        float* __restrict__ out) {
    __shared__ short Et2[2][32 * 128];
    __shared__ short Ct2[2][128 * 128];

    int bid = blockIdx.x;
    int mtile = bid & 63;
    int b = bid >> 6;
    int m0 = mtile * 32;
    int t = threadIdx.x;
    int w = t >> 6;
    int l = t & 63;
    int a15 = l & 15;
    int q = l >> 4;
    int h = a15 & 7;
    int lcc = l & 15;

    f32x4 acc[2][2] = {{{0.f,0.f,0.f,0.f},{0.f,0.f,0.f,0.f}},
                       {{0.f,0.f,0.f,0.f},{0.f,0.f,0.f,0.f}}};

    // issue buffer 0 (c-window 0): Et 2 insts/wave, Ct 8 insts/wave
    #pragma unroll
    for (int ii = 0; ii < 2; ++ii) {
        int inst = w * 2 + ii;
        gl2lds16(Eg + ((size_t)(b * L_SEQ + m0 + inst * 4 + q)) * L_SEQ + lcc * 8,
                 &Et2[0][inst * 512]);
    }
    #pragma unroll
    for (int ii = 0; ii < 8; ++ii) {
        int inst = w * 8 + ii;
        gl2lds16(CtL + ((size_t)(b * DD + inst * 4 + q)) * L_SEQ + lcc * 8,
                 &Ct2[0][inst * 512]);
    }

    for (int cs = 0; cs < 16; ++cs) {
        int bp = cs & 1;
        __syncthreads();  // drains loads into buf bp; buf bp^1 readers done last iter

        if (cs < 15) {  // issue next window into the other buffer; flies during compute
            int c0 = (cs + 1) * 128;
            #pragma unroll
            for (int ii = 0; ii < 2; ++ii) {
                int inst = w * 2 + ii;
                gl2lds16(Eg + ((size_t)(b * L_SEQ + m0 + inst * 4 + q)) * L_SEQ + c0 + lcc * 8,
                         &Et2[bp ^ 1][inst * 512]);
            }
            #pragma unroll
            for (int ii = 0; ii < 8; ++ii) {
                int inst = w * 8 + ii;
                gl2lds16(CtL + ((size_t)(b * DD + inst * 4 + q)) * L_SEQ + c0 + lcc * 8,
                         &Ct2[bp ^ 1][inst * 512]);
            }
        }

        const short* EtB = Et2[bp];
        const short* CtB = Ct2[bp];
        #pragma unroll
        for (int ks = 0; ks < 4; ++ks) {
            int aoff = ((ks * 4 + q) ^ h) * 8;
            bf16x8 a0 = *(const bf16x8*)&EtB[a15 * 128 + aoff];
            bf16x8 a1 = *(const bf16x8*)&EtB[(16 + a15) * 128 + aoff];
            bf16x8 b0 = *(const bf16x8*)&CtB[((w * 2 + 0) * 16 + a15) * 128 + aoff];
            bf16x8 b1 = *(const bf16x8*)&CtB[((w * 2 + 1) * 16 + a15) * 128 + aoff];
            acc[0][0] = __builtin_amdgcn_mfma_f32_16x16x32_bf16(a0, b0, acc[0][0], 0, 0, 0);
            acc[0][1] = __builtin_amdgcn_mfma_f32_16x16x32_bf16(a0, b1, acc[0][1], 0, 0, 0);
            acc[1][0] = __builtin_amdgcn_mfma_f32_16x16x32_bf16(a1, b0, acc[1][0], 0, 0, 0);
            acc[1][1] = __builtin_amdgcn_mfma_f32_16x16x32_bf16(a1, b1, acc[1][1], 0, 0, 0);
        }
    }

    // Epilogue: out = main(fp32) - O. D: col d = a15, row m = q*4+r.
    #pragma unroll
    for (int mg = 0; mg < 2; ++mg) {
        #pragma unroll
        for (int g = 0; g < 2; ++g) {
            int d = (w * 2 + g) * 16 + a15;
            #pragma unroll
            for (int r = 0; r < 4; ++r) {
                int m = m0 + mg * 16 + q * 4 + r;
                size_t idx = ((size_t)(b * L_SEQ + m)) * DD + d;
                out[idx] = mn[idx] - acc[mg][g][r];
            }
        }
    }
}

// ---------------------------------------------------------------------------
// Fallback path (round-2 kernels, tiny workspace)
// ---------------------------------------------------------------------------

__global__ __launch_bounds__(256, 4) void stats_fb(const float* __restrict__ ctx,
                                                   const float* __restrict__ mn,
                                                   float* __restrict__ Lg) {
    __shared__ short Cs[64 * LDA];
    __shared__ short Ms[64 * LDA];

    int bid = blockIdx.x;
    int mc = bid & 3;
    int ct = (bid >> 2) & 31;
    int b  = bid >> 7;
    int t = threadIdx.x;
    int w = t >> 6;
    int l = t & 63;
    int a15 = l & 15;
    int q = l >> 4;

    stage_tile<256>(Cs, ctx + ((size_t)b * L_SEQ + ct * 64) * DD, 64 * DD, t);

    float ls[4] = {0.f, 0.f, 0.f, 0.f};
    for (int mt = 0; mt < 8; ++mt) {
        __syncthreads();
        int m0 = (mc * 8 + mt) * 64;
        stage_tile<256>(Ms, mn + ((size_t)b * L_SEQ + m0) * DD, 64 * DD, t);
        __syncthreads();

        f32x4 acc[4] = {{0.f,0.f,0.f,0.f},{0.f,0.f,0.f,0.f},{0.f,0.f,0.f,0.f},{0.f,0.f,0.f,0.f}};
        #pragma unroll
        for (int ks = 0; ks < 4; ++ks) {
            int k0 = ks * 32 + q * 8;
            bf16x8 a = *(const bf16x8*)&Cs[(w * 16 + a15) * LDA + k0];
            #pragma unroll
            for (int g = 0; g < 4; ++g) {
                bf16x8 bb = *(const bf16x8*)&Ms[(g * 16 + a15) * LDA + k0];
                acc[g] = __builtin_amdgcn_mfma_f32_16x16x32_bf16(a, bb, acc[g], 0, 0, 0);
            }
        }
        #pragma unroll
        for (int g = 0; g < 4; ++g)
            #pragma unroll
            for (int r = 0; r < 4; ++r)
                ls[r] += __expf(acc[g][r] - SHIFT);
    }

    #pragma unroll
    for (int r = 0; r < 4; ++r) {
        float v = ls[r];
        v += __shfl_xor(v, 1);
        v += __shfl_xor(v, 2);
        v += __shfl_xor(v, 4);
        v += __shfl_xor(v, 8);
        ls[r] = v;
    }
    if (a15 == 0) {
        int c = ct * 64 + w * 16 + q * 4;
        #pragma unroll
        for (int r = 0; r < 4; ++r)
            atomicAdd(&Lg[(size_t)b * L_SEQ + c + r], ls[r]);
    }
}

__global__ __launch_bounds__(1024, 4) void attend_fb(const float* __restrict__ ctx,
                                                     const float* __restrict__ mn,
                                                     const float* __restrict__ Lg,
                                                     float* __restrict__ out) {
    __shared__ short Mt[64 * LDA];
    __shared__ short Cs[128 * LDA];
    __shared__ short Ct[128 * LDA];
    __shared__ short Ps[64 * LDA];
    __shared__ float invLs[128];

    int bid = blockIdx.x;
    int mtile = bid & 31;
    int b = bid >> 5;
    int m0 = mtile * 64;
    int t = threadIdx.x;
    int w = t >> 6;
    int l = t & 63;
    int a15 = l & 15;
    int q = l >> 4;
    int mg = w & 3;
    int pg = w >> 2;

    stage_tile<1024>(Mt, mn + ((size_t)b * L_SEQ + m0) * DD, 64 * DD, t);

    f32x4 oacc[2] = {{0.f,0.f,0.f,0.f},{0.f,0.f,0.f,0.f}};

    for (int cs = 0; cs < 16; ++cs) {
        int c0 = cs * 128;
        __syncthreads();
        stage_tile<1024>(Cs, ctx + ((size_t)b * L_SEQ + c0) * DD, 128 * DD, t);
        if (t < 128) invLs[t] = 1.0f / Lg[(size_t)b * L_SEQ + c0 + t];
        __syncthreads();

        {
            int cc = t & 127;
            int d0 = (t >> 7) * 16;
            #pragma unroll
            for (int hh = 0; hh < 2; ++hh) {
                bf16x8 v = *(const bf16x8*)&Cs[cc * LDA + d0 + hh * 8];
                #pragma unroll
                for (int j = 0; j < 8; ++j)
                    Ct[(d0 + hh * 8 + j) * LDA + cc] = v[j];
            }
        }

        f32x4 sacc[2] = {{0.f,0.f,0.f,0.f},{0.f,0.f,0.f,0.f}};
        #pragma unroll
        for (int ks = 0; ks < 4; ++ks) {
            int k0 = ks * 32 + q * 8;
            bf16x8 a = *(const bf16x8*)&Mt[(mg * 16 + a15) * LDA + k0];
            #pragma unroll
            for (int g = 0; g < 2; ++g) {
                bf16x8 bb = *(const bf16x8*)&Cs[((pg * 2 + g) * 16 + a15) * LDA + k0];
                sacc[g] = __builtin_amdgcn_mfma_f32_16x16x32_bf16(a, bb, sacc[g], 0, 0, 0);
            }
        }
        #pragma unroll
        for (int g = 0; g < 2; ++g) {
            int cl = (pg * 2 + g) * 16 + a15;
            float il = invLs[cl];
            #pragma unroll
            for (int r = 0; r < 4; ++r) {
                float p = __expf(sacc[g][r] - SHIFT) * il;
                Ps[(mg * 16 + q * 4 + r) * LDA + cl] = f2bf(p);
            }
        }
        __syncthreads();

        #pragma unroll
        for (int ks = 0; ks < 4; ++ks) {
            int k0 = ks * 32 + q * 8;
            bf16x8 a = *(const bf16x8*)&Ps[(mg * 16 + a15) * LDA + k0];
            #pragma unroll
            for (int g = 0; g < 2; ++g) {
                bf16x8 bb = *(const bf16x8*)&Ct[((pg * 2 + g) * 16 + a15) * LDA + k0];
                oacc[g] = __builtin_amdgcn_mfma_f32_16x16x32_bf16(a, bb, oacc[g], 0, 0, 0);
            }
        }
    }

    #pragma unroll
    for (int g = 0; g < 2; ++g) {
        int dl = (pg * 2 + g) * 16 + a15;
        #pragma unroll
        for (int r = 0; r < 4; ++r) {
            int ml = mg * 16 + q * 4 + r;
            size_t idx = ((size_t)b * L_SEQ + m0 + ml) * DD + dl;
            out[idx] = mn[idx] - oacc[g][r];
        }
    }
}

// ---------------------------------------------------------------------------

extern "C" void kernel_launch(void* const* d_in, const int* in_sizes, int n_in,
                              void* d_out, int out_size, void* d_ws, size_t ws_size,
                              hipStream_t stream) {
    const float* ctx = (const float*)d_in[0];  // (B, Lc, D)
    const float* mn  = (const float*)d_in[1];  // (B, Lm, D)
    float* out = (float*)d_out;                // (B, Lm, D)

    // Workspace: Lg 64 KB | Cbf 4 MB | Mbf 4 MB | CtL 4 MB | E 67 MB
    const size_t LG_BYTES = (size_t)BATCH * L_SEQ * sizeof(float);
    const size_t BF_BYTES = (size_t)BATCH * L_SEQ * DD * sizeof(short);
    const size_t E_BYTES  = (size_t)BATCH * L_SEQ * L_SEQ * sizeof(short);
    const size_t NEED = LG_BYTES + 3 * BF_BYTES + E_BYTES;

    float* Lg = (float*)d_ws;

    if (ws_size >= NEED) {
        short* Cbf = (short*)((char*)d_ws + LG_BYTES);
        short* Mbf = (short*)((char*)d_ws + LG_BYTES + BF_BYTES);
        short* CtL = (short*)((char*)d_ws + LG_BYTES + 2 * BF_BYTES);
        short* Eg  = (short*)((char*)d_ws + LG_BYTES + 3 * BF_BYTES);
        convert_kernel<<<2048, 256, 0, stream>>>(ctx, mn, Cbf, Mbf, Lg);
        stats_kernel<<<BATCH * 16 * 4, 256, 0, stream>>>(Cbf, Mbf, Lg, Eg);
        prep_kernel<<<BATCH * 16, 256, 0, stream>>>(ctx, Lg, CtL);
        attend_kernel<<<BATCH * 64, 256, 0, stream>>>(Eg, CtL, mn, out);
    } else {
        int nL = BATCH * L_SEQ;
        zero_kernel<<<(nL + 255) / 256, 256, 0, stream>>>(Lg, nL);
        stats_fb<<<BATCH * 32 * 4, 256, 0, stream>>>(ctx, mn, Lg);
        attend_fb<<<BATCH * 32, 1024, 0, stream>>>(ctx, mn, Lg, out);
    }
}